// Round 16
// baseline (64.178 us; speedup 1.0000x reference)
//
#include <hip/hip_runtime.h>
#include <math.h>

#define BG 64
#define NN 2048
#define DD 128
#define KK 1024
#define EE 4194304

// out layout (all float32, return order):
#define OFF_EI   8388608
#define OFF_BAT  16777216
#define OFF_PERM 16842752
#define OFF_SCR  16908288
#define OFF_MSK  16973824

#define TAIL_EDGE_BLOCKS 1024   // E / (256*16)
#define TAIL_GATH_BLOCKS 2048   // B*K / 32
#define SORT_BLOCKS      256    // 64 sort + 192 edge-prefetch

typedef unsigned long long u64;
typedef float f4v __attribute__((ext_vector_type(4)));
typedef int   i4v __attribute__((ext_vector_type(4)));
typedef int   i2v __attribute__((ext_vector_type(2)));

__device__ __forceinline__ void store4(float a, float b, float c, float d, float* p) {
    f4v v = {a, b, c, d};
    *(f4v*)p = v;                       // cached store (L2 write-combining path)
}

// ---------- kernel 1: score = tanh((x.w)/||w||), one wave per node ----------
// (kept byte-identical: its rounding defines the top-k tie behavior)
__global__ __launch_bounds__(256) void score_kernel(
    const float2* __restrict__ x2, const float2* __restrict__ w2,
    float* __restrict__ scores)
{
    int node = (blockIdx.x * 256 + threadIdx.x) >> 6;
    int lane = threadIdx.x & 63;
    float2 xv = x2[(size_t)node * 64 + lane];
    float2 wv = w2[lane];
    float dot = xv.x * wv.x + xv.y * wv.y;
    float ww  = wv.x * wv.x + wv.y * wv.y;
    #pragma unroll
    for (int off = 32; off >= 1; off >>= 1) {
        dot += __shfl_xor(dot, off);
        ww  += __shfl_xor(ww, off);
    }
    if (lane == 0) scores[node] = tanhf(dot / sqrtf(ww));
}

// monotone float<->uint order map (ascending)
__device__ __forceinline__ unsigned ford(float f) {
    unsigned b = __float_as_uint(f);
    return (b & 0x80000000u) ? ~b : (b | 0x80000000u);
}
__device__ __forceinline__ float forddec(unsigned u) {
    unsigned b = (u & 0x80000000u) ? (u & 0x7FFFFFFFu) : ~u;
    return __uint_as_float(b);
}

// bitonic compare-exchange via cross-lane shuffle (element held in register)
__device__ __forceinline__ u64 regswap(u64 v, int elem_idx, int j, int k) {
    u64 p = __shfl_xor(v, j, 64);
    bool dir   = ((elem_idx & k) == 0);   // true -> descending region
    bool lower = ((elem_idx & j) == 0);
    return (dir == lower) ? (v > p ? v : p) : (v < p ? v : p);
}

// ---------- kernel 2: blocks 0..63 per-graph bitonic sort; 64..255 edge prefetch ----------
__global__ __launch_bounds__(1024) void sort_kernel(
    const float* __restrict__ scores, const int* __restrict__ ei,
    i2v* __restrict__ pairs, unsigned short* __restrict__ tab16,
    unsigned* __restrict__ maskbits,
    float* __restrict__ out_batch, float* __restrict__ out_perm,
    float* __restrict__ out_score)
{
    const int b = blockIdx.x;
    const int t = threadIdx.x;

    if (b >= BG) {
        // warm edges into L2/L3 while the 64 sort blocks work (cached loads)
        const i4v* e4 = (const i4v*)ei;
        const size_t total4 = 2 * EE / 4;          // 2,097,152 int4
        size_t tid = (size_t)(b - BG) * 1024 + t;  // 0 .. 196607
        int acc = 0;
        for (size_t i = tid; i < total4; i += (size_t)(SORT_BLOCKS - BG) * 1024) {
            i4v v = e4[i];
            acc ^= v[0] ^ v[1] ^ v[2] ^ v[3];
        }
        asm volatile("" :: "v"(acc));              // keep loads live (no DCE)
        return;
    }

    __shared__ u64 keys[NN];
    __shared__ unsigned mw[NN / 32];

    float s0 = scores[b * NN + t];
    float s1 = scores[b * NN + 1024 + t];
    u64 va = ((u64)ford(s0) << 32) | (unsigned)(NN - 1 - t);
    u64 vb = ((u64)ford(s1) << 32) | (unsigned)(NN - 1 - (1024 + t));

    // stages k=2..64: entirely intra-wave, no barriers
    #pragma unroll
    for (int k = 2; k <= 64; k <<= 1)
        #pragma unroll
        for (int j = k >> 1; j >= 1; j >>= 1) {
            va = regswap(va, t, j, k);
            vb = regswap(vb, 1024 + t, j, k);
        }

    keys[t] = va; keys[1024 + t] = vb;
    if (t < NN / 32) mw[t] = 0u;
    __syncthreads();

    for (int k = 128; k <= 2048; k <<= 1) {
        for (int j = k >> 1; j >= 64; j >>= 1) {
            int i = ((t & ~(j - 1)) << 1) | (t & (j - 1));
            int p = i | j;
            u64 A = keys[i], C = keys[p];
            bool sw = ((i & k) == 0) ? (A < C) : (A > C);
            if (sw) { keys[i] = C; keys[p] = A; }
            __syncthreads();
        }
        va = keys[t]; vb = keys[1024 + t];
        #pragma unroll
        for (int j = 32; j >= 1; j >>= 1) {
            va = regswap(va, t, j, k);
            vb = regswap(vb, 1024 + t, j, k);
        }
        if (k < 2048) {
            keys[t] = va; keys[1024 + t] = vb;
            __syncthreads();
        }
    }

    int idx  = NN - 1 - (int)(va & 0xFFFFFFFFu);
    float s  = forddec((unsigned)(va >> 32));
    int gid  = b * NN + idx;
    int row  = b * KK + t;
    i2v pr; pr[0] = gid; pr[1] = __float_as_int(s);
    pairs[row]     = pr;                    // fused {gid, score} for the gather
    tab16[gid]     = (unsigned short)row;   // full new id (b*K + rank <= 65535)
    out_perm[row]  = (float)gid;
    out_score[row] = s;
    out_batch[row] = (float)b;
    atomicOr(&mw[idx >> 5], 1u << (idx & 31));
    __syncthreads();
    if (t < NN / 32) maskbits[b * (NN / 32) + t] = mw[t];
}

// ---------- fused kernel 3: edge relabel+mask (LDS bitmask) + x gather ----------
__global__ __launch_bounds__(256) void tail_kernel(
    const int* __restrict__ e0, const int* __restrict__ e1,
    const unsigned* __restrict__ mb, const unsigned short* __restrict__ tab,
    const float4* __restrict__ x4, const i2v* __restrict__ pairs,
    float* __restrict__ out)
{
    __shared__ unsigned smask[BG * NN / 32];   // 16 KB: kept-bit per node
    int bid = blockIdx.x;
    int t   = threadIdx.x;
    if (bid < TAIL_EDGE_BLOCKS) {
        // stage bitmask into LDS (coalesced, L2-resident source)
        const uint4* mb4 = (const uint4*)mb;
        uint4* sm4 = (uint4*)smask;
        #pragma unroll
        for (int u = 0; u < 4; ++u)
            sm4[u * 256 + t] = mb4[u * 256 + t];
        __syncthreads();

        float* oe0 = out + OFF_EI;
        float* oe1 = out + OFF_EI + EE;
        float* om  = out + OFF_MSK;

        size_t eb = (size_t)bid * 1024 + t;    // in int4 units; 16 edges/thread
        i4v r[4], c[4];
        #pragma unroll
        for (int u = 0; u < 4; ++u) {
            r[u] = ((const i4v*)e0)[eb + u * 256];   // cached: L3-warm from prefetch
            c[u] = ((const i4v*)e1)[eb + u * 256];
        }
        #pragma unroll
        for (int u = 0; u < 4; ++u) {
            size_t i = eb + u * 256;
            float er[4], ec[4], em[4];
            #pragma unroll
            for (int q = 0; q < 4; ++q) {
                int rq = r[u][q], cq = c[u][q];
                unsigned m = (smask[(unsigned)rq >> 5] >> (rq & 31)) &
                             (smask[(unsigned)cq >> 5] >> (cq & 31)) & 1u;
                float nr = 0.0f, nc = 0.0f;
                if (m) {
                    nr = (float)tab[rq];
                    nc = (float)tab[cq];
                }
                er[q] = nr; ec[q] = nc; em[q] = m ? 1.0f : 0.0f;
            }
            store4(er[0], er[1], er[2], er[3], oe0 + 4 * i);
            store4(ec[0], ec[1], ec[2], ec[3], oe1 + 4 * i);
            store4(em[0], em[1], em[2], em[3], om  + 4 * i);
        }
    } else {
        int gb   = bid - TAIL_EDGE_BLOCKS;
        int lane = t & 31;
        int rbase = gb * 32 + (t >> 5);        // 8 row-slots, 4 passes of stride 8
        i2v pr[4];
        #pragma unroll
        for (int p = 0; p < 4; ++p)
            pr[p] = pairs[rbase + p * 8];      // single 8B load: {gid, score}
        float4 v[4];
        #pragma unroll
        for (int p = 0; p < 4; ++p)
            v[p] = x4[(size_t)pr[p][0] * 32 + lane];
        #pragma unroll
        for (int p = 0; p < 4; ++p) {
            int row = rbase + p * 8;
            float s = __int_as_float(pr[p][1]);
            store4(v[p].x * s, v[p].y * s, v[p].z * s, v[p].w * s,
                   out + ((size_t)row * 32 + lane) * 4);
        }
    }
}

extern "C" void kernel_launch(void* const* d_in, const int* in_sizes, int n_in,
                              void* d_out, int out_size, void* d_ws, size_t ws_size,
                              hipStream_t stream)
{
    const float* x  = (const float*)d_in[0];   // [B*N, D]
    const int*   ei = (const int*)d_in[1];     // [2, E]
    const float* w  = (const float*)d_in[3];   // [D]
    float* out = (float*)d_out;

    // ws layout: scores f32[B*N] | pairs i32x2[B*K] | tab16 u16[B*N] | maskbits u32[B*N/32]
    char* wsb = (char*)d_ws;
    float*          scores   = (float*)wsb;
    i2v*            pairs    = (i2v*)(wsb + BG * NN * 4);
    unsigned short* tab16    = (unsigned short*)(wsb + (BG * NN + 2 * BG * KK) * 4);
    unsigned*       maskbits = (unsigned*)(wsb + (BG * NN + 2 * BG * KK) * 4 + BG * NN * 2);

    score_kernel<<<BG * NN / 4, 256, 0, stream>>>(
        (const float2*)x, (const float2*)w, scores);

    sort_kernel<<<SORT_BLOCKS, 1024, 0, stream>>>(
        scores, ei, pairs, tab16, maskbits,
        out + OFF_BAT, out + OFF_PERM, out + OFF_SCR);

    tail_kernel<<<TAIL_EDGE_BLOCKS + TAIL_GATH_BLOCKS, 256, 0, stream>>>(
        ei, ei + EE, maskbits, tab16,
        (const float4*)x, pairs, out);
}

// Round 17
// 62.839 us; speedup vs baseline: 1.0213x; 1.0213x over previous
//
#include <hip/hip_runtime.h>
#include <math.h>

#define BG 64
#define NN 2048
#define DD 128
#define KK 1024
#define EE 4194304

// out layout (all float32, return order):
#define OFF_EI   8388608
#define OFF_BAT  16777216
#define OFF_PERM 16842752
#define OFF_SCR  16908288
#define OFF_MSK  16973824

#define TAIL_EDGE_BLOCKS 1024   // E / (256*16)
#define TAIL_GATH_BLOCKS 2048   // B*K / 32
#define SORT_BLOCKS      256    // 64 sort + 192 edge-prefetch

typedef unsigned long long u64;
typedef float f4v __attribute__((ext_vector_type(4)));
typedef int   i4v __attribute__((ext_vector_type(4)));
typedef int   i2v __attribute__((ext_vector_type(2)));

__device__ __forceinline__ void nt_store4(float a, float b, float c, float d, float* p) {
    f4v v = {a, b, c, d};
    __builtin_nontemporal_store(v, (f4v*)p);
}

// ---------- kernel 1: score = tanh((x.w)/||w||), one wave per node ----------
// (kept byte-identical: its rounding defines the top-k tie behavior)
__global__ __launch_bounds__(256) void score_kernel(
    const float2* __restrict__ x2, const float2* __restrict__ w2,
    float* __restrict__ scores)
{
    int node = (blockIdx.x * 256 + threadIdx.x) >> 6;
    int lane = threadIdx.x & 63;
    float2 xv = x2[(size_t)node * 64 + lane];
    float2 wv = w2[lane];
    float dot = xv.x * wv.x + xv.y * wv.y;
    float ww  = wv.x * wv.x + wv.y * wv.y;
    #pragma unroll
    for (int off = 32; off >= 1; off >>= 1) {
        dot += __shfl_xor(dot, off);
        ww  += __shfl_xor(ww, off);
    }
    if (lane == 0) scores[node] = tanhf(dot / sqrtf(ww));
}

// monotone float<->uint order map (ascending)
__device__ __forceinline__ unsigned ford(float f) {
    unsigned b = __float_as_uint(f);
    return (b & 0x80000000u) ? ~b : (b | 0x80000000u);
}
__device__ __forceinline__ float forddec(unsigned u) {
    unsigned b = (u & 0x80000000u) ? (u & 0x7FFFFFFFu) : ~u;
    return __uint_as_float(b);
}

// bitonic compare-exchange via cross-lane shuffle (element held in register)
__device__ __forceinline__ u64 regswap(u64 v, int elem_idx, int j, int k) {
    u64 p = __shfl_xor(v, j, 64);
    bool dir   = ((elem_idx & k) == 0);   // true -> descending region
    bool lower = ((elem_idx & j) == 0);
    return (dir == lower) ? (v > p ? v : p) : (v < p ? v : p);
}

// ---------- kernel 2: blocks 0..63 per-graph bitonic sort; 64..255 edge prefetch ----------
__global__ __launch_bounds__(1024) void sort_kernel(
    const float* __restrict__ scores, const int* __restrict__ ei,
    i2v* __restrict__ pairs, unsigned short* __restrict__ tab16,
    unsigned* __restrict__ maskbits,
    float* __restrict__ out_batch, float* __restrict__ out_perm,
    float* __restrict__ out_score)
{
    const int b = blockIdx.x;
    const int t = threadIdx.x;

    if (b >= BG) {
        // warm edges into L2/L3 while the 64 sort blocks work (cached loads)
        const i4v* e4 = (const i4v*)ei;
        const size_t total4 = 2 * EE / 4;          // 2,097,152 int4
        size_t tid = (size_t)(b - BG) * 1024 + t;  // 0 .. 196607
        int acc = 0;
        for (size_t i = tid; i < total4; i += (size_t)(SORT_BLOCKS - BG) * 1024) {
            i4v v = e4[i];
            acc ^= v[0] ^ v[1] ^ v[2] ^ v[3];
        }
        asm volatile("" :: "v"(acc));              // keep loads live (no DCE)
        return;
    }

    __shared__ u64 keys[NN];
    __shared__ unsigned mw[NN / 32];

    float s0 = scores[b * NN + t];
    float s1 = scores[b * NN + 1024 + t];
    u64 va = ((u64)ford(s0) << 32) | (unsigned)(NN - 1 - t);
    u64 vb = ((u64)ford(s1) << 32) | (unsigned)(NN - 1 - (1024 + t));

    // stages k=2..64: entirely intra-wave, no barriers
    #pragma unroll
    for (int k = 2; k <= 64; k <<= 1)
        #pragma unroll
        for (int j = k >> 1; j >= 1; j >>= 1) {
            va = regswap(va, t, j, k);
            vb = regswap(vb, 1024 + t, j, k);
        }

    keys[t] = va; keys[1024 + t] = vb;
    if (t < NN / 32) mw[t] = 0u;
    __syncthreads();

    for (int k = 128; k <= 2048; k <<= 1) {
        for (int j = k >> 1; j >= 64; j >>= 1) {
            int i = ((t & ~(j - 1)) << 1) | (t & (j - 1));
            int p = i | j;
            u64 A = keys[i], C = keys[p];
            bool sw = ((i & k) == 0) ? (A < C) : (A > C);
            if (sw) { keys[i] = C; keys[p] = A; }
            __syncthreads();
        }
        va = keys[t]; vb = keys[1024 + t];
        #pragma unroll
        for (int j = 32; j >= 1; j >>= 1) {
            va = regswap(va, t, j, k);
            vb = regswap(vb, 1024 + t, j, k);
        }
        if (k < 2048) {
            keys[t] = va; keys[1024 + t] = vb;
            __syncthreads();
        }
    }

    int idx  = NN - 1 - (int)(va & 0xFFFFFFFFu);
    float s  = forddec((unsigned)(va >> 32));
    int gid  = b * NN + idx;
    int row  = b * KK + t;
    i2v pr; pr[0] = gid; pr[1] = __float_as_int(s);
    pairs[row]     = pr;                    // fused {gid, score} for the gather
    tab16[gid]     = (unsigned short)row;   // full new id (b*K + rank <= 65535)
    out_perm[row]  = (float)gid;
    out_score[row] = s;
    out_batch[row] = (float)b;
    atomicOr(&mw[idx >> 5], 1u << (idx & 31));
    __syncthreads();
    if (t < NN / 32) maskbits[b * (NN / 32) + t] = mw[t];
}

// ---------- fused kernel 3: edge relabel+mask (LDS bitmask) + x gather ----------
__global__ __launch_bounds__(256) void tail_kernel(
    const int* __restrict__ e0, const int* __restrict__ e1,
    const unsigned* __restrict__ mb, const unsigned short* __restrict__ tab,
    const float4* __restrict__ x4, const i2v* __restrict__ pairs,
    float* __restrict__ out)
{
    __shared__ unsigned smask[BG * NN / 32];   // 16 KB: kept-bit per node
    int bid = blockIdx.x;
    int t   = threadIdx.x;
    if (bid < TAIL_EDGE_BLOCKS) {
        // stage bitmask into LDS (coalesced, L2-resident source)
        const uint4* mb4 = (const uint4*)mb;
        uint4* sm4 = (uint4*)smask;
        #pragma unroll
        for (int u = 0; u < 4; ++u)
            sm4[u * 256 + t] = mb4[u * 256 + t];
        __syncthreads();

        float* oe0 = out + OFF_EI;
        float* oe1 = out + OFF_EI + EE;
        float* om  = out + OFF_MSK;

        size_t eb = (size_t)bid * 1024 + t;    // in int4 units; 16 edges/thread
        i4v r[4], c[4];
        #pragma unroll
        for (int u = 0; u < 4; ++u) {
            r[u] = ((const i4v*)e0)[eb + u * 256];   // cached: L3-warm from prefetch
            c[u] = ((const i4v*)e1)[eb + u * 256];
        }
        #pragma unroll
        for (int u = 0; u < 4; ++u) {
            size_t i = eb + u * 256;
            float er[4], ec[4], em[4];
            #pragma unroll
            for (int q = 0; q < 4; ++q) {
                int rq = r[u][q], cq = c[u][q];
                unsigned m = (smask[(unsigned)rq >> 5] >> (rq & 31)) &
                             (smask[(unsigned)cq >> 5] >> (cq & 31)) & 1u;
                float nr = 0.0f, nc = 0.0f;
                if (m) {
                    nr = (float)tab[rq];
                    nc = (float)tab[cq];
                }
                er[q] = nr; ec[q] = nc; em[q] = m ? 1.0f : 0.0f;
            }
            nt_store4(er[0], er[1], er[2], er[3], oe0 + 4 * i);
            nt_store4(ec[0], ec[1], ec[2], ec[3], oe1 + 4 * i);
            nt_store4(em[0], em[1], em[2], em[3], om  + 4 * i);
        }
    } else {
        int gb   = bid - TAIL_EDGE_BLOCKS;
        int lane = t & 31;
        int rbase = gb * 32 + (t >> 5);        // 8 row-slots, 4 passes of stride 8
        i2v pr[4];
        #pragma unroll
        for (int p = 0; p < 4; ++p)
            pr[p] = pairs[rbase + p * 8];      // single 8B load: {gid, score}
        float4 v[4];
        #pragma unroll
        for (int p = 0; p < 4; ++p)
            v[p] = x4[(size_t)pr[p][0] * 32 + lane];
        #pragma unroll
        for (int p = 0; p < 4; ++p) {
            int row = rbase + p * 8;
            float s = __int_as_float(pr[p][1]);
            nt_store4(v[p].x * s, v[p].y * s, v[p].z * s, v[p].w * s,
                      out + ((size_t)row * 32 + lane) * 4);
        }
    }
}

extern "C" void kernel_launch(void* const* d_in, const int* in_sizes, int n_in,
                              void* d_out, int out_size, void* d_ws, size_t ws_size,
                              hipStream_t stream)
{
    const float* x  = (const float*)d_in[0];   // [B*N, D]
    const int*   ei = (const int*)d_in[1];     // [2, E]
    const float* w  = (const float*)d_in[3];   // [D]
    float* out = (float*)d_out;

    // ws layout: scores f32[B*N] | pairs i32x2[B*K] | tab16 u16[B*N] | maskbits u32[B*N/32]
    char* wsb = (char*)d_ws;
    float*          scores   = (float*)wsb;
    i2v*            pairs    = (i2v*)(wsb + BG * NN * 4);
    unsigned short* tab16    = (unsigned short*)(wsb + (BG * NN + 2 * BG * KK) * 4);
    unsigned*       maskbits = (unsigned*)(wsb + (BG * NN + 2 * BG * KK) * 4 + BG * NN * 2);

    score_kernel<<<BG * NN / 4, 256, 0, stream>>>(
        (const float2*)x, (const float2*)w, scores);

    sort_kernel<<<SORT_BLOCKS, 1024, 0, stream>>>(
        scores, ei, pairs, tab16, maskbits,
        out + OFF_BAT, out + OFF_PERM, out + OFF_SCR);

    tail_kernel<<<TAIL_EDGE_BLOCKS + TAIL_GATH_BLOCKS, 256, 0, stream>>>(
        ei, ei + EE, maskbits, tab16,
        (const float4*)x, pairs, out);
}